// Round 1
// baseline (182.166 us; speedup 1.0000x reference)
//
#include <hip/hip_runtime.h>

#define NORD 24
#define LL 32
#define MMLEN 3073

// 1/j! for j=0..25
static constexpr float INVF[26] = {
    1.0f, 1.0f, 5.0e-1f, 1.66666672e-1f, 4.16666679e-2f, 8.33333377e-3f,
    1.38888892e-3f, 1.98412701e-4f, 2.48015876e-5f, 2.75573195e-6f,
    2.75573188e-7f, 2.50521089e-8f, 2.08767563e-9f, 1.60590438e-10f,
    1.14707458e-11f, 7.64716373e-13f, 4.77947733e-14f, 2.81145725e-15f,
    1.56192069e-16f, 8.22063525e-18f, 4.11031762e-19f, 1.95729410e-20f,
    8.89679139e-22f, 3.86817017e-23f, 1.61173757e-24f, 6.44695028e-26f};

// trapezoidal pulse, f32 arithmetic replicating the jnp reference
__device__ __forceinline__ float pulsef(float ts) {
    const float rise = 5.0e-10f;
    const float w    = 9.999999999999999e-10f;
    const float e1   = 1.4999999999999998e-9f;
    const float e2   = 1.9999999999999997e-9f;
    const float fall = 5.0e-10f;
    if (ts < rise) return ts / rise;
    if (ts < e1)   return 1.0f;
    if (ts < e2)   return 1.0f - ((ts - w) - rise) / fall;
    return 0.0f;
}

// VALU-pipe cross-lane move (DPP)
template <int CTRL>
__device__ __forceinline__ float dpp_movf(float x) {
    return __int_as_float(__builtin_amdgcn_update_dpp(
        0, __float_as_int(x), CTRL, 0xF, 0xF, true));
}

// ---------------------------------------------------------------------------
// LANE LAYOUT (changed from previous version): lane l = 4*b + q
//   b = l>>2  : branch (0..15)       q = l&3 : quarter of the 64-state chain
// Each lane holds chain positions 16q .. 16q+15 of branch b in t[0..15].
// Consequence: the per-step halo exchange (pos 16q-1 / 16q+16) is an
// INTRA-QUAD move -> single quad_perm DPP (VALU pipe, ~5cy) instead of
// ds_bpermute (LDS pipe, ~120cy) on the serial recurrence.
//   lv: lane q gets t[15] of q-1 -> quad_perm(0,0,1,2) = 0x90
//   rv: lane q gets t[0]  of q+1 -> quad_perm(1,2,3,3) = 0xF9
// ---------------------------------------------------------------------------

// Latency-tolerant 64-lane sum of values that are nonzero ONLY at lanes
// l%4==0 (the branch-head lanes). Delivers the full sum to every l%4==0
// lane. Split into issue/finalize so the 3 shfl_xor (LDS pipe) results are
// consumed ~1.5 iterations after issue (latency fully covered).
struct Red4 { float s, x16, x32, x48; };

__device__ __forceinline__ Red4 red_issue(float v) {
    v += dpp_movf<0x124>(v);   // row_ror:4 -> partial over {b, b+1} at head lanes
    v += dpp_movf<0x128>(v);   // row_ror:8 -> row's 4-branch sum at head lanes
    Red4 r;
    r.s   = v;
    r.x16 = __shfl_xor(v, 16); // other rows' head lanes hold their row sums
    r.x32 = __shfl_xor(v, 32);
    r.x48 = __shfl_xor(v, 48);
    return r;
}
__device__ __forceinline__ float red_fin(const Red4& r) {
    return (r.s + r.x16) + (r.x32 + r.x48);
}

// x <- (sum_{j<=NORD} (M dt)^j / j!) x  (PHIB=false), or the phib series
// (PHIB=true: t_0 = Bv = e_mid*xm, weights 1/(j+1)!, caller scales by dt).
//
// Mid-state pipeline: only head lanes consume mid. Using the head update
//   t0_j = al0*mid_{j-1} + be0*t1_{j-1}
// the reduce telescopes to the 2-step recurrence
//   mid_{j+1} = K1*mid_{j-1} + sum_b (cM_b*be0_b)*t1_{j-1},  K1 = sum cM*al0
// so the cross-row reduce of cb2*t1 (issued the moment nt[1] exists) has
// ~1.5 iterations of slack before its result is needed.
template <bool PHIB>
__device__ __forceinline__ void series_apply(float (&x)[16], float& xm,
                                             const float (&al)[16],
                                             const float (&be)[16],
                                             const float cM, const float cb2,
                                             const float K1, const bool head) {
    float t[16], acc[16];
    float accm, m_prev, m_cur;
    Red4 rp;
    if constexpr (PHIB) {
#pragma unroll
        for (int i = 0; i < 16; ++i) { t[i] = 0.0f; acc[i] = 0.0f; }
        accm = INVF[1] * xm;            // xm = m0 = 1/c_mid on entry
        m_prev = xm;                    // mid_0
        m_cur  = 0.0f;                  // mid_1 = sum cM*t0_0 = 0 (t_0 vec = 0)
        rp.s = rp.x16 = rp.x32 = rp.x48 = 0.0f;   // R for mid_2 = 0
    } else {
#pragma unroll
        for (int i = 0; i < 16; ++i) { t[i] = x[i]; acc[i] = x[i]; }
        accm   = xm;
        m_prev = xm;                    // mid_0
        Red4 rm = red_issue(cM * x[0]); // mid_1
        rp = red_issue(cb2 * x[1]);     // R for mid_2
        m_cur = red_fin(rm);
    }
#pragma unroll
    for (int j = 1; j <= NORD; ++j) {
        // halos: VALU quad_perm (same branch, neighbor quarter)
        const float lv = dpp_movf<0x90>(t[15]);  // from q-1
        const float rv = dpp_movf<0xF9>(t[0]);   // from q+1 (q=3: be[15]==0)
        float nt[16];
        nt[0] = al[0] * (head ? m_prev : lv) + be[0] * t[1];
#pragma unroll
        for (int i = 1; i < 15; ++i)
            nt[i] = al[i] * t[i - 1] + be[i] * t[i + 1];
        nt[15] = al[15] * t[14] + be[15] * rv;
        // issue reduce for mid_{j+2} as early as possible
        Red4 rn = red_issue(cb2 * nt[1]);
        const float f = PHIB ? INVF[j + 1] : INVF[j];
#pragma unroll
        for (int i = 0; i < 16; ++i) acc[i] = fmaf(f, nt[i], acc[i]);
        accm = fmaf(f, m_cur, accm);             // mid_j
        // finish mid_{j+1} (rp issued last iteration -> latency covered)
        const float m_next = fmaf(K1, m_prev, red_fin(rp));
        m_prev = m_cur; m_cur = m_next; rp = rn;
#pragma unroll
        for (int i = 0; i < 16; ++i) t[i] = nt[i];
    }
#pragma unroll
    for (int i = 0; i < 16; ++i) x[i] = acc[i];
    xm = accm;
}

// Meet-in-the-middle, one block, 4 waves: wave = 2*star + dir.
// dir 0 (fwd): phib series, then z31 = E^31 phib.
// dir 1 (bwd): w_a = (E^T)^a e_mid, a=0..32, folding u-weighted accumulators.
__global__ __launch_bounds__(256) void sspuf_mitm(
    const int*   __restrict__ swp,
    const float* __restrict__ mismatch,
    const float* __restrict__ gm_c,
    const float* __restrict__ gm_l,
    const float* __restrict__ c_val,
    const float* __restrict__ l_val,
    const float* __restrict__ tp,
    float*       __restrict__ out)
{
    const int tid  = threadIdx.x;
    const int wave = tid >> 6;
    const int star = wave >> 1;
    const bool bwd = wave & 1;
    const int l    = tid & 63;
    const int b    = l >> 2;           // branch
    const int q    = l & 3;            // quarter of the 64-state chain
    const bool head = (q == 0);
    const int P0i  = q << 4;
    const float dt = tp[0] / 64.0f;

    const float* mm = mismatch + star * MMLEN;
    const float* mb = mm + b * 192;
    const float swb   = (float)swp[b];
    const float c_mid = 1e-9f * (mm[MMLEN - 1] * c_val[LL]);

    __shared__ float zbuf[2][2][1032];   // [star][0]=z0 (phib), [star][1]=z31
    __shared__ float partial[2];

    // backward-wave accumulators (live across the post-barrier epilogue)
    float Pa[16], Pb[16];
    float Pam = 0.0f, Pbm = 0.0f;
#pragma unroll
    for (int i = 0; i < 16; ++i) { Pa[i] = 0.0f; Pb[i] = 0.0f; }

    if (!bwd) {
        // ---------------- forward chain ----------------
        float al[16], be[16];
#pragma unroll
        for (int i = 0; i < 16; ++i) {
            int p = P0i + i, k = p >> 1;
            if ((p & 1) == 0) {
                float Lm = 1e-9f * (mb[160 + k] * l_val[k]);
                float a  = dt * ((mb[64 + 2 * k] * gm_l[2 * k]) / Lm);
                if (k == 0) a *= swb;
                al[i] = a;
                be[i] = -dt * ((mb[64 + 2 * k + 1] * gm_l[2 * k + 1]) / Lm);
            } else {
                float C = 1e-9f * (mb[128 + k] * c_val[k]);
                al[i] = dt * ((mb[2 * k] * gm_c[2 * k]) / C);
                be[i] = (k < 31) ? (-dt * ((mb[2 * k + 1] * gm_c[2 * k + 1]) / C))
                                 : 0.0f;
            }
        }
        const float cM  = head ? (-dt * (swb / c_mid)) : 0.0f;
        const float cb2 = cM * be[0];
        const float K1  = red_fin(red_issue(cM * al[0]));

        float z[16];
        float zm = 1.0f / c_mid;
        series_apply<true>(z, zm, al, be, cM, cb2, K1, head);
#pragma unroll
        for (int i = 0; i < 16; ++i) z[i] *= dt;
        zm *= dt;

#pragma unroll
        for (int i = 0; i < 16; ++i) zbuf[star][0][l * 16 + i] = z[i];
        if (l == 0) zbuf[star][0][1024] = zm;

#pragma unroll 1
        for (int s = 0; s < 31; ++s)
            series_apply<false>(z, zm, al, be, cM, cb2, K1, head);

#pragma unroll
        for (int i = 0; i < 16; ++i) zbuf[star][1][l * 16 + i] = z[i];
        if (l == 0) zbuf[star][1][1024] = zm;
    } else {
        // ---------------- backward chain (A^T) ----------------
        float al[16], be[16];
#pragma unroll
        for (int i = 0; i < 16; ++i) {
            int p = P0i + i, k = p >> 1;
            if ((p & 1) == 0) {
                if (p == 0) {
                    al[i] = -dt * (swb / c_mid);
                } else {
                    float Cm1 = 1e-9f * (mb[128 + (k - 1)] * c_val[k - 1]);
                    al[i] = -dt * ((mb[2 * (k - 1) + 1] * gm_c[2 * (k - 1) + 1]) / Cm1);
                }
                float C = 1e-9f * (mb[128 + k] * c_val[k]);
                be[i] = dt * ((mb[2 * k] * gm_c[2 * k]) / C);
            } else {
                float Lm = 1e-9f * (mb[160 + k] * l_val[k]);
                al[i] = -dt * ((mb[64 + 2 * k + 1] * gm_l[2 * k + 1]) / Lm);
                if (k < 31) {
                    float Lp1 = 1e-9f * (mb[160 + (k + 1)] * l_val[k + 1]);
                    be[i] = dt * ((mb[64 + 2 * (k + 1)] * gm_l[2 * (k + 1)]) / Lp1);
                } else {
                    be[i] = 0.0f;
                }
            }
        }
        float Lm0 = 1e-9f * (mb[160] * l_val[0]);
        const float cM  = head ? (dt * ((swb * (mb[64] * gm_l[0])) / Lm0)) : 0.0f;
        const float cb2 = cM * be[0];
        const float K1  = red_fin(red_issue(cM * al[0]));

        // w_0 = e_mid
        float w[16];
#pragma unroll
        for (int i = 0; i < 16; ++i) w[i] = 0.0f;
        float wm = 1.0f;

#pragma unroll 1
        for (int a = 0; a <= 32; ++a) {
            const float ua = (a <= 30) ? pulsef(((float)(63 - a) + 0.5f) * dt) : 0.0f;
            const float ub = pulsef(((float)(32 - a) + 0.5f) * dt);
#pragma unroll
            for (int i = 0; i < 16; ++i) {
                Pa[i] = fmaf(ua, w[i], Pa[i]);
                Pb[i] = fmaf(ub, w[i], Pb[i]);
            }
            Pam = fmaf(ua, wm, Pam);
            Pbm = fmaf(ub, wm, Pbm);
            if (a < 32) series_apply<false>(w, wm, al, be, cM, cb2, K1, head);
        }
    }

    __syncthreads();

    if (bwd) {
        float part = 0.0f;
#pragma unroll
        for (int i = 0; i < 16; ++i)
            part += Pa[i] * zbuf[star][0][l * 16 + i]
                  + Pb[i] * zbuf[star][1][l * 16 + i];
        if (l == 0)
            part += Pam * zbuf[star][0][1024] + Pbm * zbuf[star][1][1024];
        // 64-lane sum (values nonzero on all lanes): full butterfly
        part += dpp_movf<0xB1>(part);
        part += dpp_movf<0x4E>(part);
        part += dpp_movf<0x124>(part);
        part += dpp_movf<0x128>(part);
        part += __shfl_xor(part, 16);
        part += __shfl_xor(part, 32);
        if (l == 0) partial[star] = part;
    }

    __syncthreads();
    if (tid == 0) out[0] = partial[0] - partial[1];
}

extern "C" void kernel_launch(void* const* d_in, const int* in_sizes, int n_in,
                              void* d_out, int out_size, void* d_ws, size_t ws_size,
                              hipStream_t stream) {
    const int*   swp      = (const int*)d_in[0];
    const float* mismatch = (const float*)d_in[1];
    const float* gm_c     = (const float*)d_in[2];
    const float* gm_l     = (const float*)d_in[3];
    const float* c_val    = (const float*)d_in[4];
    const float* l_val    = (const float*)d_in[5];
    const float* tp       = (const float*)d_in[6];
    float* out = (float*)d_out;

    sspuf_mitm<<<dim3(1), dim3(256), 0, stream>>>(
        swp, mismatch, gm_c, gm_l, c_val, l_val, tp, out);
}

// Round 2
// 160.486 us; speedup vs baseline: 1.1351x; 1.1351x over previous
//
#include <hip/hip_runtime.h>

#define NORD 24
#define LL 32
#define MMLEN 3073

// 1/j! for j=0..25
static constexpr float INVF[26] = {
    1.0f, 1.0f, 5.0e-1f, 1.66666672e-1f, 4.16666679e-2f, 8.33333377e-3f,
    1.38888892e-3f, 1.98412701e-4f, 2.48015876e-5f, 2.75573195e-6f,
    2.75573188e-7f, 2.50521089e-8f, 2.08767563e-9f, 1.60590438e-10f,
    1.14707458e-11f, 7.64716373e-13f, 4.77947733e-14f, 2.81145725e-15f,
    1.56192069e-16f, 8.22063525e-18f, 4.11031762e-19f, 1.95729410e-20f,
    8.89679139e-22f, 3.86817017e-23f, 1.61173757e-24f, 6.44695028e-26f};

// trapezoidal pulse, f32 arithmetic replicating the jnp reference
__device__ __forceinline__ float pulsef(float ts) {
    const float rise = 5.0e-10f;
    const float w    = 9.999999999999999e-10f;
    const float e1   = 1.4999999999999998e-9f;
    const float e2   = 1.9999999999999997e-9f;
    const float fall = 5.0e-10f;
    if (ts < rise) return ts / rise;
    if (ts < e1)   return 1.0f;
    if (ts < e2)   return 1.0f - ((ts - w) - rise) / fall;
    return 0.0f;
}

// VALU-pipe cross-lane move (DPP)
template <int CTRL>
__device__ __forceinline__ float dpp_movf(float x) {
    return __int_as_float(__builtin_amdgcn_update_dpp(
        0, __float_as_int(x), CTRL, 0xF, 0xF, true));
}

// ---------------------------------------------------------------------------
// LANE LAYOUT: lane l = 4*b + q
//   b = l>>2 : branch (0..15)     q = l&3 : quarter of the 64-state chain
// Each lane holds chain positions 16q .. 16q+15 of branch b in t[0..15].
// Halo exchange (pos 16q-1 / 16q+16) is an INTRA-QUAD quad_perm DPP
// (VALU pipe) -> the per-step loop contains ZERO LDS-pipe ops.
//   lv: lane q gets t[15] of q-1 -> quad_perm(0,0,1,2) = 0x90
//   rv: lane q gets t[0]  of q+1 -> quad_perm(1,2,3,3) = 0xF9
// ---------------------------------------------------------------------------

typedef unsigned int uint2v __attribute__((ext_vector_type(2)));

// xor-16 / xor-32 all-reduce add, VALU pipe (gfx950 permlane*_swap).
// Fallback to shfl_xor (LDS pipe) only if the builtin is unavailable.
__device__ __forceinline__ float xor16_add(float v) {
#if __has_builtin(__builtin_amdgcn_permlane16_swap)
    uint2v r = __builtin_amdgcn_permlane16_swap(
        __float_as_uint(v), __float_as_uint(v), false, false);
    return __uint_as_float(r.x) + __uint_as_float(r.y);
#else
    return v + __shfl_xor(v, 16);
#endif
}
__device__ __forceinline__ float xor32_add(float v) {
#if __has_builtin(__builtin_amdgcn_permlane32_swap)
    uint2v r = __builtin_amdgcn_permlane32_swap(
        __float_as_uint(v), __float_as_uint(v), false, false);
    return __uint_as_float(r.x) + __uint_as_float(r.y);
#else
    return v + __shfl_xor(v, 32);
#endif
}

// Full 64-lane all-reduce sum, entirely on the VALU pipe.
__device__ __forceinline__ float wave_sum(float v) {
    v += dpp_movf<0xB1>(v);   // quad_perm xor1
    v += dpp_movf<0x4E>(v);   // quad_perm xor2
    v += dpp_movf<0x124>(v);  // row_ror:4
    v += dpp_movf<0x128>(v);  // row_ror:8  -> 16-lane row sums, all lanes
    v = xor16_add(v);
    v = xor32_add(v);
    return v;
}

// x <- (sum_{j<=NORD} (M dt)^j / j!) x  (PHIB=false), or the phib series
// (PHIB=true: t_0 = Bv = e_mid*xm, weights 1/(j+1)!, caller scales by dt).
//
// Mid state m is a single scalar: m_j = sum_b cM_b * t0_{j-1}(b)  (mid row of
// M reads the PREVIOUS vector's head elements). The wave_sum is issued at the
// top of step j from the already-available t[0]; its ~40cy dependent DPP
// chain hides under the 32 independent chain FMAs. cM is nonzero only on
// head lanes (q==0), so summing all 64 lanes is exact.
template <bool PHIB>
__device__ __forceinline__ void series_apply(float (&x)[16], float& xm,
                                             const float (&al)[16],
                                             const float (&be)[16],
                                             const float cM, const bool head) {
    float t[16], acc[16];
    float accm, m_prev;
    if constexpr (PHIB) {
#pragma unroll
        for (int i = 0; i < 16; ++i) { t[i] = 0.0f; acc[i] = 0.0f; }
        accm   = INVF[1] * xm;   // xm = m0 = 1/c_mid on entry
        m_prev = xm;             // mid_0
    } else {
#pragma unroll
        for (int i = 0; i < 16; ++i) { t[i] = x[i]; acc[i] = x[i]; }
        accm   = xm;
        m_prev = xm;             // mid_0
    }
#pragma unroll
    for (int j = 1; j <= NORD; ++j) {
        // mid of t_j (depends only on t_{j-1}[0]) — issue reduce first
        const float mj = wave_sum(cM * t[0]);
        // halos: VALU quad_perm (same branch, neighbor quarter)
        const float lv = dpp_movf<0x90>(t[15]);  // from q-1
        const float rv = dpp_movf<0xF9>(t[0]);   // from q+1 (q=3: be[15]==0)
        float nt[16];
        nt[0] = al[0] * (head ? m_prev : lv) + be[0] * t[1];
#pragma unroll
        for (int i = 1; i < 15; ++i)
            nt[i] = al[i] * t[i - 1] + be[i] * t[i + 1];
        nt[15] = al[15] * t[14] + be[15] * rv;
        const float f = PHIB ? INVF[j + 1] : INVF[j];
#pragma unroll
        for (int i = 0; i < 16; ++i) acc[i] = fmaf(f, nt[i], acc[i]);
        accm = fmaf(f, mj, accm);
        m_prev = mj;
#pragma unroll
        for (int i = 0; i < 16; ++i) t[i] = nt[i];
    }
#pragma unroll
    for (int i = 0; i < 16; ++i) x[i] = acc[i];
    xm = accm;
}

// Meet-in-the-middle, one block, 4 waves: wave = 2*star + dir.
// dir 0 (fwd): phib series, then z31 = E^31 phib.
// dir 1 (bwd): w_a = (E^T)^a e_mid, a=0..32, folding u-weighted accumulators.
__global__ __launch_bounds__(256) void sspuf_mitm(
    const int*   __restrict__ swp,
    const float* __restrict__ mismatch,
    const float* __restrict__ gm_c,
    const float* __restrict__ gm_l,
    const float* __restrict__ c_val,
    const float* __restrict__ l_val,
    const float* __restrict__ tp,
    float*       __restrict__ out)
{
    const int tid  = threadIdx.x;
    const int wave = tid >> 6;
    const int star = wave >> 1;
    const bool bwd = wave & 1;
    const int l    = tid & 63;
    const int b    = l >> 2;           // branch
    const int q    = l & 3;            // quarter of the 64-state chain
    const bool head = (q == 0);
    const int P0i  = q << 4;
    const float dt = tp[0] / 64.0f;

    const float* mm = mismatch + star * MMLEN;
    const float* mb = mm + b * 192;
    const float swb   = (float)swp[b];
    const float c_mid = 1e-9f * (mm[MMLEN - 1] * c_val[LL]);

    __shared__ float zbuf[2][2][1032];   // [star][0]=z0 (phib), [star][1]=z31
    __shared__ float partial[2];

    // backward-wave accumulators (live across the post-barrier epilogue)
    float Pa[16], Pb[16];
    float Pam = 0.0f, Pbm = 0.0f;
#pragma unroll
    for (int i = 0; i < 16; ++i) { Pa[i] = 0.0f; Pb[i] = 0.0f; }

    if (!bwd) {
        // ---------------- forward chain ----------------
        float al[16], be[16];
#pragma unroll
        for (int i = 0; i < 16; ++i) {
            int p = P0i + i, k = p >> 1;
            if ((p & 1) == 0) {
                float Lm = 1e-9f * (mb[160 + k] * l_val[k]);
                float a  = dt * ((mb[64 + 2 * k] * gm_l[2 * k]) / Lm);
                if (k == 0) a *= swb;
                al[i] = a;
                be[i] = -dt * ((mb[64 + 2 * k + 1] * gm_l[2 * k + 1]) / Lm);
            } else {
                float C = 1e-9f * (mb[128 + k] * c_val[k]);
                al[i] = dt * ((mb[2 * k] * gm_c[2 * k]) / C);
                be[i] = (k < 31) ? (-dt * ((mb[2 * k + 1] * gm_c[2 * k + 1]) / C))
                                 : 0.0f;
            }
        }
        const float cM = head ? (-dt * (swb / c_mid)) : 0.0f;

        float z[16];
        float zm = 1.0f / c_mid;
        series_apply<true>(z, zm, al, be, cM, head);
#pragma unroll
        for (int i = 0; i < 16; ++i) z[i] *= dt;
        zm *= dt;

#pragma unroll
        for (int i = 0; i < 16; ++i) zbuf[star][0][l * 16 + i] = z[i];
        if (l == 0) zbuf[star][0][1024] = zm;

#pragma unroll 1
        for (int s = 0; s < 31; ++s)
            series_apply<false>(z, zm, al, be, cM, head);

#pragma unroll
        for (int i = 0; i < 16; ++i) zbuf[star][1][l * 16 + i] = z[i];
        if (l == 0) zbuf[star][1][1024] = zm;
    } else {
        // ---------------- backward chain (A^T) ----------------
        float al[16], be[16];
#pragma unroll
        for (int i = 0; i < 16; ++i) {
            int p = P0i + i, k = p >> 1;
            if ((p & 1) == 0) {
                if (p == 0) {
                    al[i] = -dt * (swb / c_mid);
                } else {
                    float Cm1 = 1e-9f * (mb[128 + (k - 1)] * c_val[k - 1]);
                    al[i] = -dt * ((mb[2 * (k - 1) + 1] * gm_c[2 * (k - 1) + 1]) / Cm1);
                }
                float C = 1e-9f * (mb[128 + k] * c_val[k]);
                be[i] = dt * ((mb[2 * k] * gm_c[2 * k]) / C);
            } else {
                float Lm = 1e-9f * (mb[160 + k] * l_val[k]);
                al[i] = -dt * ((mb[64 + 2 * k + 1] * gm_l[2 * k + 1]) / Lm);
                if (k < 31) {
                    float Lp1 = 1e-9f * (mb[160 + (k + 1)] * l_val[k + 1]);
                    be[i] = dt * ((mb[64 + 2 * (k + 1)] * gm_l[2 * (k + 1)]) / Lp1);
                } else {
                    be[i] = 0.0f;
                }
            }
        }
        float Lm0 = 1e-9f * (mb[160] * l_val[0]);
        const float cM = head ? (dt * ((swb * (mb[64] * gm_l[0])) / Lm0)) : 0.0f;

        // w_0 = e_mid
        float w[16];
#pragma unroll
        for (int i = 0; i < 16; ++i) w[i] = 0.0f;
        float wm = 1.0f;

#pragma unroll 1
        for (int a = 0; a <= 32; ++a) {
            const float ua = (a <= 30) ? pulsef(((float)(63 - a) + 0.5f) * dt) : 0.0f;
            const float ub = pulsef(((float)(32 - a) + 0.5f) * dt);
#pragma unroll
            for (int i = 0; i < 16; ++i) {
                Pa[i] = fmaf(ua, w[i], Pa[i]);
                Pb[i] = fmaf(ub, w[i], Pb[i]);
            }
            Pam = fmaf(ua, wm, Pam);
            Pbm = fmaf(ub, wm, Pbm);
            if (a < 32) series_apply<false>(w, wm, al, be, cM, head);
        }
    }

    __syncthreads();

    if (bwd) {
        float part = 0.0f;
#pragma unroll
        for (int i = 0; i < 16; ++i)
            part += Pa[i] * zbuf[star][0][l * 16 + i]
                  + Pb[i] * zbuf[star][1][l * 16 + i];
        if (l == 0)
            part += Pam * zbuf[star][0][1024] + Pbm * zbuf[star][1][1024];
        part = wave_sum(part);
        if (l == 0) partial[star] = part;
    }

    __syncthreads();
    if (tid == 0) out[0] = partial[0] - partial[1];
}

extern "C" void kernel_launch(void* const* d_in, const int* in_sizes, int n_in,
                              void* d_out, int out_size, void* d_ws, size_t ws_size,
                              hipStream_t stream) {
    const int*   swp      = (const int*)d_in[0];
    const float* mismatch = (const float*)d_in[1];
    const float* gm_c     = (const float*)d_in[2];
    const float* gm_l     = (const float*)d_in[3];
    const float* c_val    = (const float*)d_in[4];
    const float* l_val    = (const float*)d_in[5];
    const float* tp       = (const float*)d_in[6];
    float* out = (float*)d_out;

    sspuf_mitm<<<dim3(1), dim3(256), 0, stream>>>(
        swp, mismatch, gm_c, gm_l, c_val, l_val, tp, out);
}